// Round 7
// baseline (263.065 us; speedup 1.0000x reference)
//
#include <hip/hip_runtime.h>

// SplineCNN on MI355X — fused gather+GEMM per layer.
//
// Math order: s[n, k*CIN+c] = deginv * sum_{m in N(n)} basis_k(n,m) * h[m,c],
// root column appended -> per-layer dense GEMM:
//   out = relu( [s | h] @ [w; root] + bias ),  K = 10*CIN, N = 64.
// R6 proved the L2-direct gather (no h staging); R4 proved cross-dispatch L2
// locality is impossible (release/acquire at kernel boundaries). So this round
// FUSES gather and GEMM in one kernel: phase 1 gathers an M-tile's s-rows into
// a ~41KB LDS s-tile (quadrant-sorted edge lists staged per-wave in 8KB LDS,
// h read directly from L2-resident global), one barrier, phase 2 runs the
// 16x16x32 f16 MFMA GEMM with A from LDS and W streamed from L2 (<=160KB,
// read once per block), bias+relu+fp16 out fused (layer 2: + max-pool via
// uint-bitcast atomicMax, relu >= 0). The 84MB sp round-trip to HBM vanishes.
// LDS ~50KB -> 3 blocks/CU (12 waves) for gather-phase latency hiding.

#define B_   32
#define N_   512
#define F_   64
#define CAP  128          // max neighbors per node (mean ~31; P(>128) ~ 18 sigma)

typedef float f32x4 __attribute__((ext_vector_type(4)));
typedef _Float16 f16x8 __attribute__((ext_vector_type(8)));
typedef _Float16 f16x2 __attribute__((ext_vector_type(2)));

// ---------------- preprocess: quadrant-sorted edge lists ----------------
// edge record: float4 { bitcast(m), fx, fy, unused }, sorted by quad = kx0+2*ky0.
// cnt4[row] = per-quadrant counts (clamped to CAP); deginv = 1/clip(deg,1).
// Blocks 0..2047 also zero the pooled-max buffer.
__global__ __launch_bounds__(512) void preprocess_kernel(
    const float* __restrict__ adj, const float* __restrict__ coord,
    float4* __restrict__ edge, int4* __restrict__ cnt4,
    float* __restrict__ deginv, unsigned int* __restrict__ gmax) {
  int row = blockIdx.x;          // b*N + n
  int b = row >> 9;
  int tid = threadIdx.x;         // == m
  int lane = tid & 63, wave = tid >> 6;
  if (row < B_ * F_ && tid == 0) gmax[row] = 0u;
  __shared__ int wc[8][4];
  float a = adj[(size_t)row * N_ + tid];
  bool flag = (a != 0.0f);
  float cxn = coord[(size_t)row * 2 + 0];
  float cyn = coord[(size_t)row * 2 + 1];
  float cxm = coord[(size_t)(b * N_ + tid) * 2 + 0];
  float cym = coord[(size_t)(b * N_ + tid) * 2 + 1];
  float vx = (cxm - cxn + 1.0f);        // = u*2 (K-1 = 2, u in [0,1])
  float vy = (cym - cyn + 1.0f);
  float i0x = fminf(fmaxf(floorf(vx), 0.0f), 1.0f);
  float i0y = fminf(fmaxf(floorf(vy), 0.0f), 1.0f);
  float fx = vx - i0x, fy = vy - i0y;
  int quad = (int)i0x + 2 * (int)i0y;   // 0..3
  unsigned long long bq0 = __ballot(flag && quad == 0);
  unsigned long long bq1 = __ballot(flag && quad == 1);
  unsigned long long bq2 = __ballot(flag && quad == 2);
  unsigned long long bq3 = __ballot(flag && quad == 3);
  if (lane == 0) {
    wc[wave][0] = __popcll(bq0); wc[wave][1] = __popcll(bq1);
    wc[wave][2] = __popcll(bq2); wc[wave][3] = __popcll(bq3);
  }
  __syncthreads();
  int qt0 = 0, qt1 = 0, qt2 = 0, qt3 = 0;
  #pragma unroll
  for (int w2 = 0; w2 < 8; ++w2) {
    qt0 += wc[w2][0]; qt1 += wc[w2][1]; qt2 += wc[w2][2]; qt3 += wc[w2][3];
  }
  if (flag) {
    int off = 0;
    if (quad > 0) off += qt0;
    if (quad > 1) off += qt1;
    if (quad > 2) off += qt2;
    #pragma unroll
    for (int w2 = 0; w2 < 8; ++w2)
      if (w2 < wave) off += wc[w2][quad];
    unsigned long long myb = (quad == 0) ? bq0 : (quad == 1) ? bq1
                           : (quad == 2) ? bq2 : bq3;
    off += __popcll(myb & ((1ULL << lane) - 1ULL));
    if (off < CAP)
      edge[(size_t)row * CAP + off] =
          make_float4(__int_as_float(tid), fx, fy, 1.0f);
  }
  if (tid == 0) {
    int rem = CAP;
    int c0 = min(qt0, rem); rem -= c0;
    int c1 = min(qt1, rem); rem -= c1;
    int c2 = min(qt2, rem); rem -= c2;
    int c3 = min(qt3, rem);
    cnt4[row] = make_int4(c0, c1, c2, c3);
    int total = qt0 + qt1 + qt2 + qt3;
    deginv[row] = 1.0f / (float)(total > 0 ? total : 1);
  }
}

// ---------------- x fp32 [16384,128] -> fp16 [16384,128] ----------------
__global__ void convx16_kernel(const float* __restrict__ x, _Float16* __restrict__ hx) {
  int idx = blockIdx.x * blockDim.x + threadIdx.x;     // 4 elems per thread
  if (idx >= B_ * N_ * 32) return;
  float4 v = ((const float4*)x)[idx];
  f16x2 p0, p1;
  p0[0] = (_Float16)v.x; p0[1] = (_Float16)v.y;
  p1[0] = (_Float16)v.z; p1[1] = (_Float16)v.w;
  uint2 u;
  u.x = __builtin_bit_cast(unsigned, p0);
  u.y = __builtin_bit_cast(unsigned, p1);
  ((uint2*)hx)[idx] = u;
}

// ---- pack all 3 layers' [w(9 slices); root] -> Wt fp16 [64 f][KP = 10*Cin] ----
__global__ void packw3_kernel(
    const float* __restrict__ w0, const float* __restrict__ root0,
    const float* __restrict__ w1, const float* __restrict__ root1,
    const float* __restrict__ w2, const float* __restrict__ root2,
    _Float16* __restrict__ wt0, _Float16* __restrict__ wt1,
    _Float16* __restrict__ wt2) {
  int idx = blockIdx.x * blockDim.x + threadIdx.x;
  const int S0 = 64 * 1280, S1 = 64 * 640;
  const float *w, *root; _Float16* wt; int KP, CIN, r;
  if (idx < S0)            { w = w0; root = root0; wt = wt0; KP = 1280; CIN = 128; r = idx; }
  else if (idx < S0 + S1)  { w = w1; root = root1; wt = wt1; KP = 640;  CIN = 64;  r = idx - S0; }
  else if (idx < S0 + 2*S1){ w = w2; root = root2; wt = wt2; KP = 640;  CIN = 64;  r = idx - S0 - S1; }
  else return;
  int f = r / KP, k = r - f * KP;
  int ks = k / CIN, c = k - ks * CIN;
  float v = (ks < 9) ? w[((size_t)ks * CIN + c) * F_ + f]
                     : root[(size_t)c * F_ + f];
  wt[(size_t)f * KP + k] = (_Float16)v;
}

// ---------------- fused layer: gather -> LDS s-tile -> MFMA GEMM ----------------
// Block: 256 threads = 4 waves, one MT-row M-tile. Grid R/MT, XCD-swizzled so a
// batch's blocks share an XCD (h slice L2-resident). Phase 1: wave w gathers
// rows w*(MT/4).. into acc[3][3][CH] (quadrant-static targets), writes the
// s-row (9 spline cols + root passthrough) to the LDS s-tile. Phase 2: wave w
// owns output cols w*16..+15; A-frags ds_read_b128 from s-tile (stride K+8 ->
// conflict-free), B-frags dwordx4 from global W (L2). Epilogue fused.
template<int CH, int MT>
__global__ __launch_bounds__(256, 3) void fused_layer_kernel(
    const _Float16* __restrict__ hsrc,   // [16384][CIN] fp16
    const _Float16* __restrict__ Wt,     // [64][K] fp16
    const float* __restrict__ bias,
    const float4* __restrict__ edge, const int4* __restrict__ cnt4,
    const float* __restrict__ deginv,
    _Float16* __restrict__ hout,         // [16384][64] or null
    unsigned int* __restrict__ gmax) {   // [32][64] or null
  const int CIN = 64 * CH, K = 10 * CIN, SLD = K + 8;
  __shared__ __attribute__((aligned(16))) _Float16 st[MT * SLD];   // ~41 KB
  __shared__ float4 esh[4][CAP];                                    // 8 KB
  int tid = threadIdx.x, wave = tid >> 6, lane = tid & 63;
  const int BPB = 512 / MT;                 // blocks per batch (pow2)
  int xcd = blockIdx.x & 7, j = blockIdx.x >> 3;
  int b = xcd * 4 + j / BPB;
  int tile = j & (BPB - 1);
  int rowbase = (b << 9) + tile * MT;
  const _Float16* hb = hsrc + (size_t)b * N_ * CIN + lane * CH;

  // ---- phase 1: gather MT/4 rows per wave into the s-tile ----
  const int RW = MT / 4;
  for (int rr = 0; rr < RW; ++rr) {
    int tr = wave * RW + rr;
    int row = rowbase + tr;
    int4 c4 = cnt4[row];
    int e1 = c4.x, e2 = e1 + c4.y, e3 = e2 + c4.z, e4 = e3 + c4.w;
    size_t ebase = (size_t)row * CAP;
    for (int i = lane; i < e4; i += 64)
      esh[wave][i] = edge[ebase + i];       // wave-private region
    float di = deginv[row];
    float acc[3][3][CH] = {};

#define EDGE_BODY(E, KX, KY) {                                        \
    float4 er = esh[wave][E];                                         \
    int m = __float_as_int(er.x);                                     \
    float hv[CH];                                                     \
    if (CH == 1) {                                                    \
      hv[0] = (float)hb[(size_t)m * 64];                              \
    } else {                                                          \
      unsigned u = *(const unsigned*)&hb[(size_t)m * 128];            \
      f16x2 hp = __builtin_bit_cast(f16x2, u);                        \
      hv[0] = (float)hp[0]; hv[CH - 1] = (float)hp[1];                \
    }                                                                 \
    float fx = er.y, fy = er.z;                                       \
    float gx = 1.0f - fx, gy = 1.0f - fy;                             \
    float w00 = gx * gy, w01 = gx * fy, w10 = fx * gy, w11 = fx * fy; \
    _Pragma("unroll")                                                 \
    for (int c = 0; c < CH; ++c) {                                    \
      acc[KX][KY][c]         += w00 * hv[c];                          \
      acc[KX][KY + 1][c]     += w01 * hv[c];                          \
      acc[KX + 1][KY][c]     += w10 * hv[c];                          \
      acc[KX + 1][KY + 1][c] += w11 * hv[c];                          \
    } }

    #pragma unroll 4
    for (int e = 0; e < e1; ++e) EDGE_BODY(e, 0, 0)    // kx0=0, ky0=0
    #pragma unroll 4
    for (int e = e1; e < e2; ++e) EDGE_BODY(e, 1, 0)   // kx0=1, ky0=0
    #pragma unroll 4
    for (int e = e2; e < e3; ++e) EDGE_BODY(e, 0, 1)   // kx0=0, ky0=1
    #pragma unroll 4
    for (int e = e3; e < e4; ++e) EDGE_BODY(e, 1, 1)   // kx0=1, ky0=1
#undef EDGE_BODY

    // store s-row: col k*CIN + lane*CH, k = kx*3+ky (reference reshape order)
    _Float16* sr = st + tr * SLD + lane * CH;
    #pragma unroll
    for (int kx = 0; kx < 3; ++kx)
      #pragma unroll
      for (int ky = 0; ky < 3; ++ky) {
        int k = kx * 3 + ky;
        if (CH == 1) {
          sr[k * CIN] = (_Float16)(acc[kx][ky][0] * di);
        } else {
          f16x2 p;
          p[0] = (_Float16)(acc[kx][ky][0] * di);
          p[1] = (_Float16)(acc[kx][ky][CH - 1] * di);
          *(f16x2*)&sr[k * CIN] = p;
        }
      }
    // root column: h passthrough
    if (CH == 1) {
      sr[9 * CIN] = hb[(size_t)(row - (b << 9)) * 64];
    } else {
      *(unsigned*)&sr[9 * CIN] = *(const unsigned*)&hb[(size_t)(row - (b << 9)) * 128];
    }
  }
  __syncthreads();

  // ---- phase 2: GEMM from LDS s-tile; wave owns cols wave*16..+15 ----
  const int CT = MT / 16;
  int lr = lane & 15, quad = lane >> 4;
  f32x4 acc2[CT];
  #pragma unroll
  for (int ct = 0; ct < CT; ++ct) acc2[ct] = (f32x4){0.f, 0.f, 0.f, 0.f};
  const _Float16* wrow = Wt + (size_t)(wave * 16 + lr) * K + quad * 8;
  #pragma unroll 4
  for (int ks = 0; ks < K; ks += 32) {
    f16x8 bf = *(const f16x8*)(wrow + ks);
    #pragma unroll
    for (int ct = 0; ct < CT; ++ct) {
      f16x8 af = *(const f16x8*)&st[(ct * 16 + lr) * SLD + ks + quad * 8];
      acc2[ct] = __builtin_amdgcn_mfma_f32_16x16x32_f16(af, bf, acc2[ct], 0, 0, 0);
    }
  }
  // epilogue: C layout col = lane&15, row = quad*4 + r (verified)
  int f = wave * 16 + lr;
  float bs = bias[f];
  #pragma unroll
  for (int ct = 0; ct < CT; ++ct) {
    float vmax = 0.0f;
    #pragma unroll
    for (int r = 0; r < 4; ++r) {
      int m = rowbase + ct * 16 + (quad << 2) + r;
      float v = fmaxf(acc2[ct][r] + bs, 0.0f);
      if (hout) hout[(size_t)m * F_ + f] = (_Float16)v;
      vmax = fmaxf(vmax, v);
    }
    if (gmax) atomicMax(&gmax[(b << 6) + f], __float_as_uint(vmax));
  }
}

// ---------------- FC from pooled features ----------------
__global__ __launch_bounds__(64) void fc_kernel(
    const float* __restrict__ g, const float* __restrict__ fcw,
    const float* __restrict__ fcb, float* __restrict__ out) {
  int b = blockIdx.x;
  int f = threadIdx.x;
  __shared__ float gs[64];
  gs[f] = g[b * F_ + f];
  __syncthreads();
  if (f < 10) {
    float s = fcb[f];
    #pragma unroll
    for (int c = 0; c < 64; ++c) s += gs[c] * fcw[c * 10 + f];
    out[b * 10 + f] = s;
  }
}

extern "C" void kernel_launch(void* const* d_in, const int* in_sizes, int n_in,
                              void* d_out, int out_size, void* d_ws, size_t ws_size,
                              hipStream_t stream) {
  const float* x     = (const float*)d_in[0];
  const float* coord = (const float*)d_in[1];
  const float* adj   = (const float*)d_in[2];
  const float* w0    = (const float*)d_in[3];
  const float* root0 = (const float*)d_in[4];
  const float* b0    = (const float*)d_in[5];
  const float* w1    = (const float*)d_in[6];
  const float* root1 = (const float*)d_in[7];
  const float* b1    = (const float*)d_in[8];
  const float* w2    = (const float*)d_in[9];
  const float* root2 = (const float*)d_in[10];
  const float* b2    = (const float*)d_in[11];
  const float* fcw   = (const float*)d_in[12];
  const float* fcb   = (const float*)d_in[13];
  float* out = (float*)d_out;

  char* ws = (char*)d_ws;
  size_t off = 0;
  auto alloc = [&](size_t bytes) {
    void* p = ws + off;
    off = (off + bytes + 255) & ~(size_t)255;
    return p;
  };
  const int R = B_ * N_;  // 16384
  float4* edge    = (float4*)alloc((size_t)R * CAP * 16);
  int4*   cnt4    = (int4*)  alloc((size_t)R * 16);
  float*  deginv  = (float*) alloc((size_t)R * 4);
  _Float16* hx    = (_Float16*)alloc((size_t)R * 128 * 2);   // fp16 x
  _Float16* wt0   = (_Float16*)alloc((size_t)64 * 1280 * 2);
  _Float16* wt1   = (_Float16*)alloc((size_t)64 * 640 * 2);
  _Float16* wt2   = (_Float16*)alloc((size_t)64 * 640 * 2);
  _Float16* hA    = (_Float16*)alloc((size_t)R * 64 * 2);
  _Float16* hB    = (_Float16*)alloc((size_t)R * 64 * 2);
  unsigned int* gmax = (unsigned int*)alloc((size_t)B_ * F_ * 4);

  preprocess_kernel<<<R, 512, 0, stream>>>(adj, coord, edge, cnt4, deginv, gmax);
  convx16_kernel<<<(R * 32 + 255) / 256, 256, 0, stream>>>(x, hx);
  packw3_kernel<<<(64 * (1280 + 640 + 640) + 255) / 256, 256, 0, stream>>>(
      w0, root0, w1, root1, w2, root2, wt0, wt1, wt2);

  // layer 0: CIN=128 (MT=16), layer 1/2: CIN=64 (MT=32); fused gather+GEMM
  fused_layer_kernel<2, 16><<<R / 16, 256, 0, stream>>>(
      hx, wt0, b0, edge, cnt4, deginv, hA, nullptr);
  fused_layer_kernel<1, 32><<<R / 32, 256, 0, stream>>>(
      hA, wt1, b1, edge, cnt4, deginv, hB, nullptr);
  fused_layer_kernel<1, 32><<<R / 32, 256, 0, stream>>>(
      hB, wt2, b2, edge, cnt4, deginv, nullptr, gmax);

  fc_kernel<<<B_, 64, 0, stream>>>((const float*)gmax, fcw, fcb, out);
}